// Round 2
// baseline (313.108 us; speedup 1.0000x reference)
//
#include <hip/hip_runtime.h>
#include <math.h>
#include <stdint.h>

#define BATCH 64
#define N_OBJ 32
#define NP 8732
#define NC 81
#define THRESH 0.5f

// ---------------------------------------------------------------------------
// ws layout:
//   ovp    : float[BATCH*NP]   best IoU per (image, prior)
//   objp   : int  [BATCH*NP]   argmax object per (image, prior)
//   ce_neg : float[BATCH*NP]   CE of negatives (0 at positives)
//   pfo    : int  [BATCH*N_OBJ] argmax prior per (image, object)
//   n_pos  : int  [BATCH]
//   scal   : float[3]          {conf_pos, conf_hard_neg, loc_sum}
// ---------------------------------------------------------------------------

__global__ void k_zero(int* n_pos, float* scal) {
    int t = threadIdx.x;
    if (t < BATCH) n_pos[t] = 0;
    if (t == 0) { scal[0] = 0.f; scal[1] = 0.f; scal[2] = 0.f; }
}

__device__ __forceinline__ float iou_box_prior(float x1, float y1, float x2, float y2,
                                               float areaA, float4 pr, float areaB) {
    float iw = fminf(x2, pr.z) - fmaxf(x1, pr.x); iw = fmaxf(iw, 0.f);
    float ih = fminf(y2, pr.w) - fmaxf(y1, pr.y); ih = fmaxf(ih, 0.f);
    float inter = iw * ih;
    return inter / (areaA + areaB - inter);
}

// per (image, prior): best object (first-occurrence argmax like jnp)
__global__ void k_match_prior(const float* __restrict__ boxes,
                              const float* __restrict__ priors,
                              float* __restrict__ ovp, int* __restrict__ objp) {
    int i = blockIdx.y;
    __shared__ float bx[N_OBJ * 4];
    int t = threadIdx.x;
    if (t < N_OBJ * 4) bx[t] = boxes[i * N_OBJ * 4 + t];
    __syncthreads();
    int p = blockIdx.x * blockDim.x + t;
    if (p >= NP) return;
    float4 pr = ((const float4*)priors)[p];
    float areaB = (pr.z - pr.x) * (pr.w - pr.y);
    float best = -1.0f; int bestj = 0;
    for (int j = 0; j < N_OBJ; ++j) {
        float x1 = bx[j * 4 + 0], y1 = bx[j * 4 + 1], x2 = bx[j * 4 + 2], y2 = bx[j * 4 + 3];
        float areaA = (x2 - x1) * (y2 - y1);
        float v = iou_box_prior(x1, y1, x2, y2, areaA, pr, areaB);
        if (v > best) { best = v; bestj = j; }   // strict > keeps FIRST max
    }
    ovp[i * NP + p] = best;
    objp[i * NP + p] = bestj;
}

// per (image, object): best prior (first-index tie-break)
__global__ void k_match_obj(const float* __restrict__ boxes,
                            const float* __restrict__ priors,
                            int* __restrict__ pfo) {
    int j = blockIdx.x, i = blockIdx.y;
    const float* bp = boxes + (i * N_OBJ + j) * 4;
    float x1 = bp[0], y1 = bp[1], x2 = bp[2], y2 = bp[3];
    float areaA = (x2 - x1) * (y2 - y1);
    float best = -1.f; int bestp = NP;
    for (int p = threadIdx.x; p < NP; p += blockDim.x) {
        float4 pr = ((const float4*)priors)[p];
        float areaB = (pr.z - pr.x) * (pr.w - pr.y);
        float v = iou_box_prior(x1, y1, x2, y2, areaA, pr, areaB);
        if (v > best) { best = v; bestp = p; }   // p ascending -> first max kept
    }
    __shared__ float sv[256];
    __shared__ int   si[256];
    int t = threadIdx.x;
    sv[t] = best; si[t] = bestp;
    __syncthreads();
    for (int s = 128; s > 0; s >>= 1) {
        if (t < s) {
            float v2 = sv[t + s]; int i2 = si[t + s];
            if (v2 > sv[t] || (v2 == sv[t] && i2 < si[t])) { sv[t] = v2; si[t] = i2; }
        }
        __syncthreads();
    }
    if (t == 0) pfo[i * N_OBJ + j] = si[0];
}

// sequential last-wins forced matches (matches .at[].set realization)
__global__ void k_force(const int* __restrict__ pfo,
                        float* __restrict__ ovp, int* __restrict__ objp) {
    int i = blockIdx.x * blockDim.x + threadIdx.x;
    if (i >= BATCH) return;
    for (int j = 0; j < N_OBJ; ++j) {
        int p = pfo[i * N_OBJ + j];
        objp[i * NP + p] = j;
        ovp[i * NP + p] = 1.0f;
    }
}

// one wave per prior: log-softmax CE + positive-prior stats + loc L1
__global__ void k_ce(const float* __restrict__ scores,
                     const float* __restrict__ plocs,
                     const float* __restrict__ boxes,
                     const int*   __restrict__ labels,
                     const float* __restrict__ priors,
                     const float* __restrict__ ovp,
                     const int*   __restrict__ objp,
                     float* __restrict__ ce_neg,
                     int* __restrict__ n_pos, float* __restrict__ scal) {
    int i = blockIdx.y;
    int wave = threadIdx.x >> 6;
    int lane = threadIdx.x & 63;
    int wavesPerRow = gridDim.x * (blockDim.x >> 6);
    for (int p = blockIdx.x * (blockDim.x >> 6) + wave; p < NP; p += wavesPerRow) {
        const float* s = scores + ((size_t)i * NP + p) * NC;
        float v0 = s[lane];
        bool has1 = (lane + 64) < NC;
        float v1 = has1 ? s[lane + 64] : -INFINITY;
        float m = fmaxf(v0, v1);
        #pragma unroll
        for (int off = 32; off; off >>= 1) m = fmaxf(m, __shfl_xor(m, off));
        float e = __expf(v0 - m) + (has1 ? __expf(v1 - m) : 0.f);
        #pragma unroll
        for (int off = 32; off; off >>= 1) e += __shfl_xor(e, off);
        float lse = m + __logf(e);

        int   obj = objp[i * NP + p];
        float ov  = ovp[i * NP + p];
        int   lab = (ov < THRESH) ? 0 : labels[i * N_OBJ + obj];
        float slab = (lab < 64) ? __shfl(v0, lab) : __shfl(v1, lab - 64);
        float ce = lse - slab;

        if (lane == 0) {
            if (lab != 0) {
                atomicAdd(&n_pos[i], 1);
                atomicAdd(&scal[0], ce);
                const float* bp = boxes + (i * N_OBJ + obj) * 4;
                float x1 = bp[0], y1 = bp[1], x2 = bp[2], y2 = bp[3];
                float bcx = (x1 + x2) * 0.5f, bcy = (y1 + y2) * 0.5f;
                float bw = x2 - x1, bh = y2 - y1;
                float4 pr = ((const float4*)priors)[p];
                float g0 = (bcx - pr.x) / (pr.z / 10.0f);
                float g1 = (bcy - pr.y) / (pr.w / 10.0f);
                float g2 = logf(bw / pr.z) * 5.0f;
                float g3 = logf(bh / pr.w) * 5.0f;
                const float* pl = plocs + ((size_t)i * NP + p) * 4;
                float l = fabsf(pl[0] - g0) + fabsf(pl[1] - g1)
                        + fabsf(pl[2] - g2) + fabsf(pl[3] - g3);
                atomicAdd(&scal[2], l);
                ce_neg[i * NP + p] = 0.f;
            } else {
                ce_neg[i * NP + p] = ce;
            }
        }
    }
}

// exact top-k sum per row via bit-pattern binary search (all ce >= 0)
__global__ void k_topk(const float* __restrict__ ce_neg,
                       const int* __restrict__ n_pos, float* __restrict__ scal) {
    int i = blockIdx.x;
    __shared__ float row[NP];
    __shared__ int   cnt_s[4];
    __shared__ float sum_s[4];
    int t = threadIdx.x;
    for (int p = t; p < NP; p += 256) row[p] = ce_neg[i * NP + p];
    __syncthreads();
    int k = 3 * n_pos[i];
    if (k > NP) k = NP;
    if (k <= 0) return;

    unsigned lo = 0u, hi = 0x7F800001u;   // cnt(lo)=NP>=k ; cnt(hi)=0<k
    while (hi - lo > 1u) {
        unsigned mid = lo + ((hi - lo) >> 1);
        int c = 0;
        for (int p = t; p < NP; p += 256) c += (__float_as_uint(row[p]) >= mid) ? 1 : 0;
        #pragma unroll
        for (int off = 32; off; off >>= 1) c += __shfl_xor(c, off);
        if ((t & 63) == 0) cnt_s[t >> 6] = c;
        __syncthreads();
        int total = cnt_s[0] + cnt_s[1] + cnt_s[2] + cnt_s[3];
        __syncthreads();
        if (total >= k) lo = mid; else hi = mid;
    }
    float vk = __uint_as_float(lo);   // k-th largest value (an actual element)

    float s = 0.f; int c = 0;
    for (int p = t; p < NP; p += 256) {
        float x = row[p];
        if (x > vk) { s += x; c++; }
    }
    #pragma unroll
    for (int off = 32; off; off >>= 1) { s += __shfl_xor(s, off); c += __shfl_xor(c, off); }
    if ((t & 63) == 0) { sum_s[t >> 6] = s; cnt_s[t >> 6] = c; }
    __syncthreads();
    if (t == 0) {
        float st = sum_s[0] + sum_s[1] + sum_s[2] + sum_s[3];
        int   ct = cnt_s[0] + cnt_s[1] + cnt_s[2] + cnt_s[3];
        atomicAdd(&scal[1], st + (float)(k - ct) * vk);
    }
}

__global__ void k_final(const int* __restrict__ n_pos,
                        const float* __restrict__ scal, float* __restrict__ out) {
    if (threadIdx.x == 0) {
        int nt = 0;
        for (int i = 0; i < BATCH; ++i) nt += n_pos[i];
        float nf = (float)nt;
        out[0] = (scal[1] + scal[0]) / nf + scal[2] / (nf * 4.0f);
    }
}

extern "C" void kernel_launch(void* const* d_in, const int* in_sizes, int n_in,
                              void* d_out, int out_size, void* d_ws, size_t ws_size,
                              hipStream_t stream) {
    const float* plocs  = (const float*)d_in[0];
    const float* scores = (const float*)d_in[1];
    const float* boxes  = (const float*)d_in[2];
    const int*   labels = (const int*)d_in[3];
    const float* priors = (const float*)d_in[4];
    float* out = (float*)d_out;

    char* ws = (char*)d_ws;
    size_t bp = (size_t)BATCH * NP * 4;
    float* ovp    = (float*)(ws);
    int*   objp   = (int*)  (ws + bp);
    float* ce_neg = (float*)(ws + 2 * bp);
    int*   pfo    = (int*)  (ws + 3 * bp);
    int*   n_pos  = pfo + BATCH * N_OBJ;
    float* scal   = (float*)(n_pos + BATCH);

    hipLaunchKernelGGL(k_zero, dim3(1), dim3(64), 0, stream, n_pos, scal);
    hipLaunchKernelGGL(k_match_prior, dim3((NP + 255) / 256, BATCH), dim3(256), 0, stream,
                       boxes, priors, ovp, objp);
    hipLaunchKernelGGL(k_match_obj, dim3(N_OBJ, BATCH), dim3(256), 0, stream,
                       boxes, priors, pfo);
    hipLaunchKernelGGL(k_force, dim3(1), dim3(64), 0, stream, pfo, ovp, objp);
    hipLaunchKernelGGL(k_ce, dim3(35, BATCH), dim3(256), 0, stream,
                       scores, plocs, boxes, labels, priors, ovp, objp, ce_neg, n_pos, scal);
    hipLaunchKernelGGL(k_topk, dim3(BATCH), dim3(256), 0, stream, ce_neg, n_pos, scal);
    hipLaunchKernelGGL(k_final, dim3(1), dim3(1), 0, stream, n_pos, scal, out);
}

// Round 3
// 199.255 us; speedup vs baseline: 1.5714x; 1.5714x over previous
//
#include <hip/hip_runtime.h>
#include <math.h>
#include <stdint.h>

#define BATCH 64
#define N_OBJ 32
#define NP 8732
#define NC 81
#define THRESH 0.5f
#define ROWS_PER_BLK 64

// ---------------------------------------------------------------------------
// ws layout:
//   ovp    : float[BATCH*NP]   best IoU per (image, prior)
//   objp   : int  [BATCH*NP]   argmax object per (image, prior)
//   ce_neg : float[BATCH*NP]   CE of negatives (0 at positives)
//   pfo    : int  [BATCH*N_OBJ] argmax prior per (image, object)
//   n_pos  : int  [BATCH]
//   scal   : float[3]          {conf_pos, conf_hard_neg, loc_sum}
// ---------------------------------------------------------------------------

__global__ void k_zero(int* n_pos, float* scal) {
    int t = threadIdx.x;
    if (t < BATCH) n_pos[t] = 0;
    if (t == 0) { scal[0] = 0.f; scal[1] = 0.f; scal[2] = 0.f; }
}

__device__ __forceinline__ float iou_box_prior(float x1, float y1, float x2, float y2,
                                               float areaA, float4 pr, float areaB) {
    float iw = fminf(x2, pr.z) - fmaxf(x1, pr.x); iw = fmaxf(iw, 0.f);
    float ih = fminf(y2, pr.w) - fmaxf(y1, pr.y); ih = fmaxf(ih, 0.f);
    float inter = iw * ih;
    return inter / (areaA + areaB - inter);
}

// per (image, prior): best object (first-occurrence argmax like jnp)
__global__ void k_match_prior(const float* __restrict__ boxes,
                              const float* __restrict__ priors,
                              float* __restrict__ ovp, int* __restrict__ objp) {
    int i = blockIdx.y;
    __shared__ float bx[N_OBJ * 4];
    int t = threadIdx.x;
    if (t < N_OBJ * 4) bx[t] = boxes[i * N_OBJ * 4 + t];
    __syncthreads();
    int p = blockIdx.x * blockDim.x + t;
    if (p >= NP) return;
    float4 pr = ((const float4*)priors)[p];
    float areaB = (pr.z - pr.x) * (pr.w - pr.y);
    float best = -1.0f; int bestj = 0;
    for (int j = 0; j < N_OBJ; ++j) {
        float x1 = bx[j * 4 + 0], y1 = bx[j * 4 + 1], x2 = bx[j * 4 + 2], y2 = bx[j * 4 + 3];
        float areaA = (x2 - x1) * (y2 - y1);
        float v = iou_box_prior(x1, y1, x2, y2, areaA, pr, areaB);
        if (v > best) { best = v; bestj = j; }   // strict > keeps FIRST max
    }
    ovp[i * NP + p] = best;
    objp[i * NP + p] = bestj;
}

// per (image, object): best prior (first-index tie-break)
__global__ void k_match_obj(const float* __restrict__ boxes,
                            const float* __restrict__ priors,
                            int* __restrict__ pfo) {
    int j = blockIdx.x, i = blockIdx.y;
    const float* bp = boxes + (i * N_OBJ + j) * 4;
    float x1 = bp[0], y1 = bp[1], x2 = bp[2], y2 = bp[3];
    float areaA = (x2 - x1) * (y2 - y1);
    float best = -1.f; int bestp = NP;
    for (int p = threadIdx.x; p < NP; p += blockDim.x) {
        float4 pr = ((const float4*)priors)[p];
        float areaB = (pr.z - pr.x) * (pr.w - pr.y);
        float v = iou_box_prior(x1, y1, x2, y2, areaA, pr, areaB);
        if (v > best) { best = v; bestp = p; }   // p ascending -> first max kept
    }
    __shared__ float sv[256];
    __shared__ int   si[256];
    int t = threadIdx.x;
    sv[t] = best; si[t] = bestp;
    __syncthreads();
    for (int s = 128; s > 0; s >>= 1) {
        if (t < s) {
            float v2 = sv[t + s]; int i2 = si[t + s];
            if (v2 > sv[t] || (v2 == sv[t] && i2 < si[t])) { sv[t] = v2; si[t] = i2; }
        }
        __syncthreads();
    }
    if (t == 0) pfo[i * N_OBJ + j] = si[0];
}

// sequential last-wins forced matches (matches .at[].set realization)
__global__ void k_force(const int* __restrict__ pfo,
                        float* __restrict__ ovp, int* __restrict__ objp) {
    int i = blockIdx.x * blockDim.x + threadIdx.x;
    if (i >= BATCH) return;
    for (int j = 0; j < N_OBJ; ++j) {
        int p = pfo[i * N_OBJ + j];
        objp[i * NP + p] = j;
        ovp[i * NP + p] = 1.0f;
    }
}

// LDS-staged CE: block loads 64 contiguous prior-rows coalesced, then
// 4 threads/row reduce from registers. One global atomic set per block.
__global__ void __launch_bounds__(256)
k_ce(const float* __restrict__ scores,
     const float* __restrict__ plocs,
     const float* __restrict__ boxes,
     const int*   __restrict__ labels,
     const float* __restrict__ priors,
     const float* __restrict__ ovp,
     const int*   __restrict__ objp,
     float* __restrict__ ce_neg,
     int* __restrict__ n_pos, float* __restrict__ scal) {
    __shared__ float smem[ROWS_PER_BLK * NC];
    __shared__ float acc_cpos, acc_loc;
    __shared__ int   acc_np;
    int i  = blockIdx.y;
    int p0 = blockIdx.x * ROWS_PER_BLK;
    int rows = NP - p0; if (rows > ROWS_PER_BLK) rows = ROWS_PER_BLK;
    int t = threadIdx.x;
    if (t == 0) { acc_cpos = 0.f; acc_loc = 0.f; acc_np = 0; }

    const float* g = scores + ((size_t)i * NP + p0) * NC;
    int cnt = rows * NC;
    #pragma unroll 7
    for (int idx = t; idx < cnt; idx += 256) smem[idx] = g[idx];
    __syncthreads();

    int r = t >> 2, c = t & 3;
    bool active = (r < rows);
    float x[21];
    float m = -INFINITY;
    int nx = 0;
    if (active) {
        for (int e = c; e < NC; e += 4) { x[nx] = smem[r * NC + e]; m = fmaxf(m, x[nx]); ++nx; }
    }
    m = fmaxf(m, __shfl_xor(m, 1));
    m = fmaxf(m, __shfl_xor(m, 2));
    float s = 0.f;
    for (int q = 0; q < nx; ++q) s += __expf(x[q] - m);
    s += __shfl_xor(s, 1);
    s += __shfl_xor(s, 2);

    if (active && c == 0) {
        float lse = m + __logf(s);
        int gi = i * NP + p0 + r;
        int   obj = objp[gi];
        float ov  = ovp[gi];
        int   lab = (ov < THRESH) ? 0 : labels[i * N_OBJ + obj];
        float ce = lse - smem[r * NC + lab];
        if (lab != 0) {
            atomicAdd(&acc_np, 1);
            atomicAdd(&acc_cpos, ce);
            const float* bp = boxes + (i * N_OBJ + obj) * 4;
            float x1 = bp[0], y1 = bp[1], x2 = bp[2], y2 = bp[3];
            float bcx = (x1 + x2) * 0.5f, bcy = (y1 + y2) * 0.5f;
            float bw = x2 - x1, bh = y2 - y1;
            float4 pr = ((const float4*)priors)[p0 + r];
            float g0 = (bcx - pr.x) / (pr.z / 10.0f);
            float g1 = (bcy - pr.y) / (pr.w / 10.0f);
            float g2 = logf(bw / pr.z) * 5.0f;
            float g3 = logf(bh / pr.w) * 5.0f;
            const float* pl = plocs + (size_t)gi * 4;
            float l = fabsf(pl[0] - g0) + fabsf(pl[1] - g1)
                    + fabsf(pl[2] - g2) + fabsf(pl[3] - g3);
            atomicAdd(&acc_loc, l);
            ce_neg[gi] = 0.f;
        } else {
            ce_neg[gi] = ce;
        }
    }
    __syncthreads();
    if (t == 0 && acc_np > 0) {
        atomicAdd(&n_pos[i], acc_np);
        atomicAdd(&scal[0], acc_cpos);
        atomicAdd(&scal[2], acc_loc);
    }
}

// exact top-k sum per row; row held in registers (35/thread), 31-pass
// binary search on the float bit pattern (all ce >= 0, pads = 0 are inert)
__global__ void __launch_bounds__(256)
k_topk(const float* __restrict__ ce_neg,
       const int* __restrict__ n_pos, float* __restrict__ scal) {
    int i = blockIdx.x;
    int t = threadIdx.x;
    float x[35];
    #pragma unroll
    for (int j = 0; j < 35; ++j) {
        int p = t + j * 256;
        x[j] = (p < NP) ? ce_neg[i * NP + p] : 0.f;
    }
    int k = 3 * n_pos[i];
    if (k > NP) k = NP;
    if (k <= 0) return;                     // uniform across block

    __shared__ int   cnt_s[4];
    __shared__ float sum_s[4];
    unsigned lo = 0u, hi = 0x7F800001u;     // cnt(lo)=all >= k ; cnt(hi)=0 < k
    while (hi - lo > 1u) {
        unsigned mid = lo + ((hi - lo) >> 1);
        int c = 0;
        #pragma unroll
        for (int j = 0; j < 35; ++j) c += (__float_as_uint(x[j]) >= mid) ? 1 : 0;
        #pragma unroll
        for (int off = 32; off; off >>= 1) c += __shfl_xor(c, off);
        if ((t & 63) == 0) cnt_s[t >> 6] = c;
        __syncthreads();
        int total = cnt_s[0] + cnt_s[1] + cnt_s[2] + cnt_s[3];
        __syncthreads();
        if (total >= k) lo = mid; else hi = mid;
    }
    float vk = __uint_as_float(lo);         // k-th largest (an actual element, or 0)

    float s = 0.f; int c = 0;
    #pragma unroll
    for (int j = 0; j < 35; ++j) {
        float v = x[j];
        if (v > vk) { s += v; c++; }
    }
    #pragma unroll
    for (int off = 32; off; off >>= 1) { s += __shfl_xor(s, off); c += __shfl_xor(c, off); }
    if ((t & 63) == 0) { sum_s[t >> 6] = s; cnt_s[t >> 6] = c; }
    __syncthreads();
    if (t == 0) {
        float st = sum_s[0] + sum_s[1] + sum_s[2] + sum_s[3];
        int   ct = cnt_s[0] + cnt_s[1] + cnt_s[2] + cnt_s[3];
        atomicAdd(&scal[1], st + (float)(k - ct) * vk);
    }
}

__global__ void k_final(const int* __restrict__ n_pos,
                        const float* __restrict__ scal, float* __restrict__ out) {
    if (threadIdx.x == 0) {
        int nt = 0;
        for (int i = 0; i < BATCH; ++i) nt += n_pos[i];
        float nf = (float)nt;
        out[0] = (scal[1] + scal[0]) / nf + scal[2] / (nf * 4.0f);
    }
}

extern "C" void kernel_launch(void* const* d_in, const int* in_sizes, int n_in,
                              void* d_out, int out_size, void* d_ws, size_t ws_size,
                              hipStream_t stream) {
    const float* plocs  = (const float*)d_in[0];
    const float* scores = (const float*)d_in[1];
    const float* boxes  = (const float*)d_in[2];
    const int*   labels = (const int*)d_in[3];
    const float* priors = (const float*)d_in[4];
    float* out = (float*)d_out;

    char* ws = (char*)d_ws;
    size_t bp = (size_t)BATCH * NP * 4;
    float* ovp    = (float*)(ws);
    int*   objp   = (int*)  (ws + bp);
    float* ce_neg = (float*)(ws + 2 * bp);
    int*   pfo    = (int*)  (ws + 3 * bp);
    int*   n_pos  = pfo + BATCH * N_OBJ;
    float* scal   = (float*)(n_pos + BATCH);

    hipLaunchKernelGGL(k_zero, dim3(1), dim3(64), 0, stream, n_pos, scal);
    hipLaunchKernelGGL(k_match_prior, dim3((NP + 255) / 256, BATCH), dim3(256), 0, stream,
                       boxes, priors, ovp, objp);
    hipLaunchKernelGGL(k_match_obj, dim3(N_OBJ, BATCH), dim3(256), 0, stream,
                       boxes, priors, pfo);
    hipLaunchKernelGGL(k_force, dim3(1), dim3(64), 0, stream, pfo, ovp, objp);
    hipLaunchKernelGGL(k_ce, dim3((NP + ROWS_PER_BLK - 1) / ROWS_PER_BLK, BATCH), dim3(256), 0, stream,
                       scores, plocs, boxes, labels, priors, ovp, objp, ce_neg, n_pos, scal);
    hipLaunchKernelGGL(k_topk, dim3(BATCH), dim3(256), 0, stream, ce_neg, n_pos, scal);
    hipLaunchKernelGGL(k_final, dim3(1), dim3(1), 0, stream, n_pos, scal, out);
}

// Round 4
// 191.694 us; speedup vs baseline: 1.6334x; 1.0394x over previous
//
#include <hip/hip_runtime.h>
#include <math.h>
#include <stdint.h>

#define BATCH 64
#define N_OBJ 32
#define NP 8732
#define NC 81
#define THRESH 0.5f
#define ROWS_PER_BLK 64

// ---------------------------------------------------------------------------
// ws layout:
//   ovp    : float[BATCH*NP]   best IoU per (image, prior)
//   objp   : int  [BATCH*NP]   argmax object per (image, prior)
//   ce_neg : float[BATCH*NP]   CE of negatives (0 at positives)
//   pfo    : int  [BATCH*N_OBJ] argmax prior per (image, object)
//   n_pos  : int  [BATCH]
//   scal   : float[3]          {conf_pos, conf_hard_neg, loc_sum}
// ---------------------------------------------------------------------------

__device__ __forceinline__ float iou_box_prior(float x1, float y1, float x2, float y2,
                                               float areaA, float4 pr, float areaB) {
    float iw = fminf(x2, pr.z) - fmaxf(x1, pr.x); iw = fmaxf(iw, 0.f);
    float ih = fminf(y2, pr.w) - fmaxf(y1, pr.y); ih = fmaxf(ih, 0.f);
    float inter = iw * ih;
    return inter / (areaA + areaB - inter);
}

// per (image, prior): best object (first-occurrence argmax like jnp)
// also zeroes n_pos/scal (replaces k_zero; completes before k_ce runs)
__global__ void k_match_prior(const float* __restrict__ boxes,
                              const float* __restrict__ priors,
                              float* __restrict__ ovp, int* __restrict__ objp,
                              int* __restrict__ n_pos, float* __restrict__ scal) {
    int i = blockIdx.y;
    int t = threadIdx.x;
    if (blockIdx.x == 0 && i == 0) {
        if (t < BATCH) n_pos[t] = 0;
        if (t < 3) scal[t] = 0.f;
    }
    __shared__ float bx[N_OBJ * 4];
    if (t < N_OBJ * 4) bx[t] = boxes[i * N_OBJ * 4 + t];
    __syncthreads();
    int p = blockIdx.x * blockDim.x + t;
    if (p >= NP) return;
    float4 pr = ((const float4*)priors)[p];
    float areaB = (pr.z - pr.x) * (pr.w - pr.y);
    float best = -1.0f; int bestj = 0;
    #pragma unroll
    for (int j = 0; j < N_OBJ; ++j) {
        float x1 = bx[j * 4 + 0], y1 = bx[j * 4 + 1], x2 = bx[j * 4 + 2], y2 = bx[j * 4 + 3];
        float areaA = (x2 - x1) * (y2 - y1);
        float v = iou_box_prior(x1, y1, x2, y2, areaA, pr, areaB);
        if (v > best) { best = v; bestj = j; }   // strict > keeps FIRST max
    }
    ovp[i * NP + p] = best;
    objp[i * NP + p] = bestj;
}

// per (image, object): best prior (first-index tie-break)
__global__ void k_match_obj(const float* __restrict__ boxes,
                            const float* __restrict__ priors,
                            int* __restrict__ pfo) {
    int j = blockIdx.x, i = blockIdx.y;
    const float* bp = boxes + (i * N_OBJ + j) * 4;
    float x1 = bp[0], y1 = bp[1], x2 = bp[2], y2 = bp[3];
    float areaA = (x2 - x1) * (y2 - y1);
    float best = -1.f; int bestp = NP;
    for (int p = threadIdx.x; p < NP; p += blockDim.x) {
        float4 pr = ((const float4*)priors)[p];
        float areaB = (pr.z - pr.x) * (pr.w - pr.y);
        float v = iou_box_prior(x1, y1, x2, y2, areaA, pr, areaB);
        if (v > best) { best = v; bestp = p; }   // p ascending -> first max kept
    }
    __shared__ float sv[256];
    __shared__ int   si[256];
    int t = threadIdx.x;
    sv[t] = best; si[t] = bestp;
    __syncthreads();
    for (int s = 128; s > 0; s >>= 1) {
        if (t < s) {
            float v2 = sv[t + s]; int i2 = si[t + s];
            if (v2 > sv[t] || (v2 == sv[t] && i2 < si[t])) { sv[t] = v2; si[t] = i2; }
        }
        __syncthreads();
    }
    if (t == 0) pfo[i * N_OBJ + j] = si[0];
}

// sequential last-wins forced matches (matches .at[].set realization)
__global__ void k_force(const int* __restrict__ pfo,
                        float* __restrict__ ovp, int* __restrict__ objp) {
    int i = blockIdx.x * blockDim.x + threadIdx.x;
    if (i >= BATCH) return;
    for (int j = 0; j < N_OBJ; ++j) {
        int p = pfo[i * N_OBJ + j];
        objp[i * NP + p] = j;
        ovp[i * NP + p] = 1.0f;
    }
}

// LDS-staged CE: float4-stage 64 contiguous prior-rows, then 4 threads/row
// reduce via two LDS passes (no per-thread arrays -> no scratch).
__global__ void __launch_bounds__(256)
k_ce(const float* __restrict__ scores,
     const float* __restrict__ plocs,
     const float* __restrict__ boxes,
     const int*   __restrict__ labels,
     const float* __restrict__ priors,
     const float* __restrict__ ovp,
     const int*   __restrict__ objp,
     float* __restrict__ ce_neg,
     int* __restrict__ n_pos, float* __restrict__ scal) {
    __shared__ __align__(16) float smem[ROWS_PER_BLK * NC];
    __shared__ float acc_cpos, acc_loc;
    __shared__ int   acc_np;
    int i  = blockIdx.y;
    int p0 = blockIdx.x * ROWS_PER_BLK;
    int rows = NP - p0; if (rows > ROWS_PER_BLK) rows = ROWS_PER_BLK;
    int t = threadIdx.x;
    if (t == 0) { acc_cpos = 0.f; acc_loc = 0.f; acc_np = 0; }

    // stage rows*NC floats; base element offset and count are multiples of 4
    const float4* g4 = (const float4*)(scores + ((size_t)i * NP + p0) * NC);
    float4* s4 = (float4*)smem;
    int cnt4 = (rows * NC) >> 2;
    for (int idx = t; idx < cnt4; idx += 256) s4[idx] = g4[idx];
    __syncthreads();

    int r = t >> 2, c = t & 3;
    bool active = (r < rows);
    const float* row = smem + r * NC;

    float m = -INFINITY;
    if (active) {
        for (int e = c; e < NC; e += 4) m = fmaxf(m, row[e]);
    }
    m = fmaxf(m, __shfl_xor(m, 1));
    m = fmaxf(m, __shfl_xor(m, 2));
    float s = 0.f;
    if (active) {
        for (int e = c; e < NC; e += 4) s += __expf(row[e] - m);
    }
    s += __shfl_xor(s, 1);
    s += __shfl_xor(s, 2);

    if (active && c == 0) {
        float lse = m + __logf(s);
        int gi = i * NP + p0 + r;
        int   obj = objp[gi];
        float ov  = ovp[gi];
        int   lab = (ov < THRESH) ? 0 : labels[i * N_OBJ + obj];
        float ce = lse - row[lab];
        if (lab != 0) {
            atomicAdd(&acc_np, 1);
            atomicAdd(&acc_cpos, ce);
            const float* bp = boxes + (i * N_OBJ + obj) * 4;
            float x1 = bp[0], y1 = bp[1], x2 = bp[2], y2 = bp[3];
            float bcx = (x1 + x2) * 0.5f, bcy = (y1 + y2) * 0.5f;
            float bw = x2 - x1, bh = y2 - y1;
            float4 pr = ((const float4*)priors)[p0 + r];
            float g0 = (bcx - pr.x) / (pr.z / 10.0f);
            float g1 = (bcy - pr.y) / (pr.w / 10.0f);
            float g2 = logf(bw / pr.z) * 5.0f;
            float g3 = logf(bh / pr.w) * 5.0f;
            const float* pl = plocs + (size_t)gi * 4;
            float l = fabsf(pl[0] - g0) + fabsf(pl[1] - g1)
                    + fabsf(pl[2] - g2) + fabsf(pl[3] - g3);
            atomicAdd(&acc_loc, l);
            ce_neg[gi] = 0.f;
        } else {
            ce_neg[gi] = ce;
        }
    }
    __syncthreads();
    if (t == 0 && acc_np > 0) {
        atomicAdd(&n_pos[i], acc_np);
        atomicAdd(&scal[0], acc_cpos);
        atomicAdd(&scal[2], acc_loc);
    }
}

// exact top-k sum per row; row held in registers (35/thread, static unroll),
// 31-pass binary search on the float bit pattern (all ce >= 0)
__global__ void __launch_bounds__(256)
k_topk(const float* __restrict__ ce_neg,
       const int* __restrict__ n_pos, float* __restrict__ scal) {
    int i = blockIdx.x;
    int t = threadIdx.x;
    float x[35];
    #pragma unroll
    for (int j = 0; j < 35; ++j) {
        int p = t + j * 256;
        x[j] = (p < NP) ? ce_neg[i * NP + p] : 0.f;
    }
    int k = 3 * n_pos[i];
    if (k > NP) k = NP;
    if (k <= 0) return;                     // uniform across block

    __shared__ int   cnt_s[4];
    __shared__ float sum_s[4];
    unsigned lo = 0u, hi = 0x7F800001u;     // cnt(lo)=all >= k ; cnt(hi)=0 < k
    while (hi - lo > 1u) {
        unsigned mid = lo + ((hi - lo) >> 1);
        int c = 0;
        #pragma unroll
        for (int j = 0; j < 35; ++j) c += (__float_as_uint(x[j]) >= mid) ? 1 : 0;
        #pragma unroll
        for (int off = 32; off; off >>= 1) c += __shfl_xor(c, off);
        if ((t & 63) == 0) cnt_s[t >> 6] = c;
        __syncthreads();
        int total = cnt_s[0] + cnt_s[1] + cnt_s[2] + cnt_s[3];
        __syncthreads();
        if (total >= k) lo = mid; else hi = mid;
    }
    float vk = __uint_as_float(lo);         // k-th largest (an actual element, or 0)

    float s = 0.f; int c = 0;
    #pragma unroll
    for (int j = 0; j < 35; ++j) {
        float v = x[j];
        if (v > vk) { s += v; c++; }
    }
    #pragma unroll
    for (int off = 32; off; off >>= 1) { s += __shfl_xor(s, off); c += __shfl_xor(c, off); }
    if ((t & 63) == 0) { sum_s[t >> 6] = s; cnt_s[t >> 6] = c; }
    __syncthreads();
    if (t == 0) {
        float st = sum_s[0] + sum_s[1] + sum_s[2] + sum_s[3];
        int   ct = cnt_s[0] + cnt_s[1] + cnt_s[2] + cnt_s[3];
        atomicAdd(&scal[1], st + (float)(k - ct) * vk);
    }
}

__global__ void k_final(const int* __restrict__ n_pos,
                        const float* __restrict__ scal, float* __restrict__ out) {
    if (threadIdx.x == 0) {
        int nt = 0;
        for (int i = 0; i < BATCH; ++i) nt += n_pos[i];
        float nf = (float)nt;
        out[0] = (scal[1] + scal[0]) / nf + scal[2] / (nf * 4.0f);
    }
}

extern "C" void kernel_launch(void* const* d_in, const int* in_sizes, int n_in,
                              void* d_out, int out_size, void* d_ws, size_t ws_size,
                              hipStream_t stream) {
    const float* plocs  = (const float*)d_in[0];
    const float* scores = (const float*)d_in[1];
    const float* boxes  = (const float*)d_in[2];
    const int*   labels = (const int*)d_in[3];
    const float* priors = (const float*)d_in[4];
    float* out = (float*)d_out;

    char* ws = (char*)d_ws;
    size_t bp = (size_t)BATCH * NP * 4;
    float* ovp    = (float*)(ws);
    int*   objp   = (int*)  (ws + bp);
    float* ce_neg = (float*)(ws + 2 * bp);
    int*   pfo    = (int*)  (ws + 3 * bp);
    int*   n_pos  = pfo + BATCH * N_OBJ;
    float* scal   = (float*)(n_pos + BATCH);

    hipLaunchKernelGGL(k_match_prior, dim3((NP + 255) / 256, BATCH), dim3(256), 0, stream,
                       boxes, priors, ovp, objp, n_pos, scal);
    hipLaunchKernelGGL(k_match_obj, dim3(N_OBJ, BATCH), dim3(256), 0, stream,
                       boxes, priors, pfo);
    hipLaunchKernelGGL(k_force, dim3(1), dim3(64), 0, stream, pfo, ovp, objp);
    hipLaunchKernelGGL(k_ce, dim3((NP + ROWS_PER_BLK - 1) / ROWS_PER_BLK, BATCH), dim3(256), 0, stream,
                       scores, plocs, boxes, labels, priors, ovp, objp, ce_neg, n_pos, scal);
    hipLaunchKernelGGL(k_topk, dim3(BATCH), dim3(256), 0, stream, ce_neg, n_pos, scal);
    hipLaunchKernelGGL(k_final, dim3(1), dim3(1), 0, stream, n_pos, scal, out);
}